// Round 4
// baseline (531.764 us; speedup 1.0000x reference)
//
#include <hip/hip_runtime.h>
#include <stdint.h>

#define DEV static __device__ __forceinline__

typedef unsigned short u16;
typedef u16  u16x8 __attribute__((ext_vector_type(8)));
typedef u16  u16x4 __attribute__((ext_vector_type(4)));
typedef float f32x4 __attribute__((ext_vector_type(4)));
typedef short s16x8 __attribute__((ext_vector_type(8)));   // 8 bf16 as shorts (guide-verified MFMA frag type)

// problem dims
#define BB 16
#define CC 1024
#define SS 1024      // Sq = 32*32
#define CTX 2048
#define SKK 256
#define NH 16
#define HD 64
#define NG 32
#define ATT_SCALE 0.35355339059327373f   // 1/64^0.25

DEV u16 f2bf(float f) {                    // fp32 -> bf16 RNE
  uint32_t u = __float_as_uint(f);
  return (u16)((u + 0x7fffu + ((u >> 16) & 1u)) >> 16);
}
DEV s16x8 ld8(const u16* p) { return __builtin_bit_cast(s16x8, *(const u16x8*)p); }
DEV f32x4 zero4() { f32x4 z = {0.f, 0.f, 0.f, 0.f}; return z; }

// async global->LDS, 16B per lane. LDS dst is wave-uniform base + lane*16.
// AS-typed pointers obtained via integer casts (LDS aperture is 4GB-aligned,
// so truncating a flat LDS address to 32 bits yields the LDS offset).
DEV void gload_lds16(const void* g, const void* l) {
  __builtin_amdgcn_global_load_lds(
      (const __attribute__((address_space(1))) unsigned int*)(uintptr_t)g,
      (__attribute__((address_space(3))) unsigned int*)(uint32_t)(uintptr_t)l,
      16, 0, 0);
}

// ---------------- weight fp32 -> bf16 ----------------
__global__ __launch_bounds__(256) void cvt_bf16(const float* __restrict__ in,
                                                u16* __restrict__ out, int n4) {
  int i = blockIdx.x * 256 + threadIdx.x;
  if (i < n4) {
    f32x4 v = ((const f32x4*)in)[i];
    u16x4 o; o[0]=f2bf(v[0]); o[1]=f2bf(v[1]); o[2]=f2bf(v[2]); o[3]=f2bf(v[3]);
    ((u16x4*)out)[i] = o;
  }
}

// ---------------- GroupNorm stats for x: group = 32 contiguous channels x 1024
// spatial = one contiguous 32768-float span.
__global__ __launch_bounds__(256) void gn_stats_x(const float* __restrict__ x,
                                                  float* __restrict__ st) {
  const int b = blockIdx.x >> 5, g = blockIdx.x & 31;
  const float* p = x + ((size_t)b * CC + g * 32) * SS;
  const int tid = threadIdx.x;
  float s = 0.f, ss = 0.f;
  for (int it = 0; it < 32; ++it) {
    f32x4 v = *(const f32x4*)(p + it * 1024 + tid * 4);
    s  += v[0] + v[1] + v[2] + v[3];
    ss += v[0]*v[0] + v[1]*v[1] + v[2]*v[2] + v[3]*v[3];
  }
  __shared__ float red[512];
  red[tid] = s; red[256 + tid] = ss;
  __syncthreads();
  for (int o = 128; o > 0; o >>= 1) {
    if (tid < o) { red[tid] += red[tid + o]; red[256 + tid] += red[256 + tid + o]; }
    __syncthreads();
  }
  if (tid == 0) {
    float mean = red[0] * (1.f / 32768.f);
    float var  = red[256] * (1.f / 32768.f) - mean * mean;
    st[(b * 32 + g) * 2 + 0] = mean;
    st[(b * 32 + g) * 2 + 1] = rsqrtf(var + 1e-5f);
  }
}

// normalize x and write TRANSPOSED bf16: xnT[b][s][c]  (c contiguous = MFMA-K-contig)
__global__ __launch_bounds__(256) void gn_apply_tr_x(const float* __restrict__ x,
                                                     const float* __restrict__ st,
                                                     const float* __restrict__ gamma,
                                                     const float* __restrict__ beta,
                                                     u16* __restrict__ xnT) {
  __shared__ float t[64][65];
  const int b = blockIdx.z, c0 = blockIdx.y * 64, s0 = blockIdx.x * 64;
  const int tid = threadIdx.x, j = tid & 63, i0 = tid >> 6;
  for (int it = 0; it < 16; ++it) {
    int i = it * 4 + i0;            // channel within tile
    int c = c0 + i;
    int g = c >> 5;
    float mean = st[(b * 32 + g) * 2], rstd = st[(b * 32 + g) * 2 + 1];
    float v = x[((size_t)b * CC + c) * SS + s0 + j];
    t[i][j] = (v - mean) * rstd * gamma[c] + beta[c];
  }
  __syncthreads();
  for (int it = 0; it < 16; ++it) {
    int jj = it * 4 + i0;           // s within tile
    xnT[((size_t)b * SS + s0 + jj) * CC + c0 + j] = f2bf(t[j][jj]);
  }
}

// ---------------- GroupNorm stats for ctx^T: group = 64 contiguous ctx-channels
// over all 256 positions (context layout [b][s'][ch] -> strided reads).
__global__ __launch_bounds__(256) void gn_stats_c(const float* __restrict__ ctx,
                                                  float* __restrict__ st) {
  const int b = blockIdx.x >> 5, g = blockIdx.x & 31;
  const float* p = ctx + (size_t)b * SKK * CTX + g * 64;
  const int ch = threadIdx.x & 63, r0 = threadIdx.x >> 6;
  float s = 0.f, ss = 0.f;
  for (int it = 0; it < 64; ++it) {
    float v = p[(size_t)(it * 4 + r0) * CTX + ch];
    s += v; ss += v * v;
  }
  __shared__ float red[512];
  const int tid = threadIdx.x;
  red[tid] = s; red[256 + tid] = ss;
  __syncthreads();
  for (int o = 128; o > 0; o >>= 1) {
    if (tid < o) { red[tid] += red[tid + o]; red[256 + tid] += red[256 + tid + o]; }
    __syncthreads();
  }
  if (tid == 0) {
    float mean = red[0] * (1.f / 16384.f);
    float var  = red[256] * (1.f / 16384.f) - mean * mean;
    st[(b * 32 + g) * 2 + 0] = mean;
    st[(b * 32 + g) * 2 + 1] = rsqrtf(var + 1e-5f);
  }
}

// normalize ctx elementwise -> bf16 ctxn[b][s'][ch] (already K-contig layout)
__global__ __launch_bounds__(256) void gn_apply_c(const float* __restrict__ ctx,
                                                  const float* __restrict__ st,
                                                  const float* __restrict__ gamma,
                                                  const float* __restrict__ beta,
                                                  u16* __restrict__ out) {
  size_t i = ((size_t)blockIdx.x * 256 + threadIdx.x) * 4;
  int ch = (int)(i & 2047);
  int bs = (int)(i >> 11);
  int b = bs >> 8;
  int g = ch >> 6;
  float mean = st[(b * 32 + g) * 2], rstd = st[(b * 32 + g) * 2 + 1];
  f32x4 v  = *(const f32x4*)(ctx + i);
  f32x4 ga = *(const f32x4*)(gamma + ch);
  f32x4 be = *(const f32x4*)(beta + ch);
  u16x4 o;
  o[0] = f2bf((v[0] - mean) * rstd * ga[0] + be[0]);
  o[1] = f2bf((v[1] - mean) * rstd * ga[1] + be[1]);
  o[2] = f2bf((v[2] - mean) * rstd * ga[2] + be[2]);
  o[3] = f2bf((v[3] - mean) * rstd * ga[3] + be[3]);
  *(u16x4*)(out + i) = o;
}

__global__ __launch_bounds__(256) void mask_bias_k(const int* __restrict__ mask,
                                                   float* __restrict__ mb) {
  int i = blockIdx.x * 256 + threadIdx.x;
  mb[i] = mask[i] ? 0.f : -1e9f;
}

// ---------------- generic bf16 GEMM, m97 structure: C[m][n] = sum_k A[m][k]*Bt[n][k]
// 128x128 tile, BK=32, 4 waves (2x2), global_load_lds staging, 2-barrier loop.
// EPI 0: bf16 out, val=(acc+bias[col]) * (col<Nthresh ? scl : 1)
// EPI 1: f32  out, val = resid[idx] + acc + bias[row]
template <int BM, int BN, int EPI>
__global__ __launch_bounds__(256) void gemm_bt(
    const u16* __restrict__ A, const u16* __restrict__ Bt, void* __restrict__ Cout,
    const float* __restrict__ bias, const float* __restrict__ resid,
    int K, int lda, int ldb, int ldc,
    long strideAb, long strideBb, long strideCb, int Nthresh, float scl) {
  constexpr int MF = BM / 32, NF = BN / 32;        // frags per wave
  constexpr int ACH = BM / 16, BCH = BN / 16;      // 1KB staging chunks
  __shared__ alignas(16) u16 lds_a[BM * 32];
  __shared__ alignas(16) u16 lds_b[BN * 32];
  const int tid = threadIdx.x, wid = tid >> 6, lane = tid & 63;
  const int wm = wid >> 1, wn = wid & 1;
  const int b = blockIdx.z;
  const u16* Ab = A + (long)b * strideAb + (long)blockIdx.x * BM * lda;
  const u16* Bb = Bt + (long)b * strideBb + (long)blockIdx.y * BN * ldb;
  const int srow = lane >> 2, scol = (lane & 3) * 8;
  const int fr = lane & 15, fk = (lane >> 4) * 8;

  f32x4 acc[MF][NF];
#pragma unroll
  for (int m = 0; m < MF; ++m)
#pragma unroll
    for (int n = 0; n < NF; ++n) acc[m][n] = zero4();

  for (int kt = 0; kt < K; kt += 32) {
    __syncthreads();
#pragma unroll
    for (int c = 0; c < ACH / 4; ++c) {
      int ch = wid + c * 4;
      gload_lds16(Ab + (long)(ch * 16 + srow) * lda + kt + scol, &lds_a[ch * 512]);
    }
#pragma unroll
    for (int c = 0; c < BCH / 4; ++c) {
      int ch = wid + c * 4;
      gload_lds16(Bb + (long)(ch * 16 + srow) * ldb + kt + scol, &lds_b[ch * 512]);
    }
    __syncthreads();
    s16x8 af[MF], bfr[NF];
#pragma unroll
    for (int m = 0; m < MF; ++m) af[m] = ld8(&lds_a[(wm * (BM / 2) + m * 16 + fr) * 32 + fk]);
#pragma unroll
    for (int n = 0; n < NF; ++n) bfr[n] = ld8(&lds_b[(wn * (BN / 2) + n * 16 + fr) * 32 + fk]);
#pragma unroll
    for (int m = 0; m < MF; ++m)
#pragma unroll
      for (int n = 0; n < NF; ++n)
        acc[m][n] = __builtin_amdgcn_mfma_f32_16x16x32_bf16(af[m], bfr[n], acc[m][n], 0, 0, 0);
  }

  const int rowb = blockIdx.x * BM + wm * (BM / 2) + ((lane >> 4) << 2);
  const int colb = blockIdx.y * BN + wn * (BN / 2) + fr;
#pragma unroll
  for (int m = 0; m < MF; ++m) {
#pragma unroll
    for (int n = 0; n < NF; ++n) {
      int col = colb + n * 16;
      f32x4 v = acc[m][n];
      if constexpr (EPI == 0) {
        float bia = bias[col];
        float s = (col < Nthresh) ? scl : 1.0f;
        u16* C = (u16*)Cout + (long)b * strideCb;
#pragma unroll
        for (int i = 0; i < 4; ++i) {
          int row = rowb + m * 16 + i;
          C[(long)row * ldc + col] = f2bf((v[i] + bia) * s);
        }
      } else {
        float* C = (float*)Cout + (long)b * strideCb;
        const float* R = resid + (long)b * strideCb;
#pragma unroll
        for (int i = 0; i < 4; ++i) {
          int row = rowb + m * 16 + i;
          long idx = (long)row * ldc + col;
          C[idx] = R[idx] + v[i] + bias[row];
        }
      }
    }
  }
}

// ---------------- transpose V half of kv_t -> v2[b][o(1024)][s'(256)]
__global__ __launch_bounds__(256) void transpose_v(const u16* __restrict__ kvt,
                                                   u16* __restrict__ v2) {
  __shared__ u16 t[64][66];
  const int b = blockIdx.z, s0 = blockIdx.y * 64, o0 = blockIdx.x * 64;
  const int tid = threadIdx.x, j = tid & 63, i0 = tid >> 6;
#pragma unroll
  for (int it = 0; it < 16; ++it) {
    int i = it * 4 + i0;   // s' row
    t[i][j] = kvt[((long)b * SKK + s0 + i) * CTX + CC + o0 + j];
  }
  __syncthreads();
#pragma unroll
  for (int it = 0; it < 16; ++it) {
    int oi = it * 4 + i0;  // o row
    v2[((long)b * CC + o0 + oi) * SKK + s0 + j] = t[j][oi];
  }
}

// ---------------- fused attention: per block = one (b,h) and 64 q-rows.
// QK^T (K operand direct from global/L2) -> masked softmax in-register
// (row lives in 16 lanes x 16 frags) -> P via XOR-swizzled wave-private LDS -> PV.
__global__ __launch_bounds__(256) void attn_fused(const u16* __restrict__ qt,
                                                  const u16* __restrict__ kvt,
                                                  const u16* __restrict__ v2,
                                                  const float* __restrict__ mbias,
                                                  u16* __restrict__ at) {
  __shared__ alignas(16) u16 p_lds[4 * 16 * 256];   // 32KB, wave-private 16x256 each
  const int b = blockIdx.z, h = blockIdx.y, t0 = blockIdx.x * 64;
  const int tid = threadIdx.x, wid = tid >> 6, lane = tid & 63;
  const int fr = lane & 15, fk = (lane >> 4) * 8;
  const int trow = t0 + wid * 16 + fr;

  const u16* qp = qt + ((long)b * SS + trow) * CC + h * HD + fk;
  s16x8 aq0 = ld8(qp), aq1 = ld8(qp + 32);

  f32x4 sc[16];
  const u16* kp = kvt + (long)b * SKK * CTX + (long)fr * CTX + h * HD + fk;
#pragma unroll
  for (int nf = 0; nf < 16; ++nf) {
    s16x8 b0 = ld8(kp + (long)nf * 16 * CTX);
    s16x8 b1 = ld8(kp + (long)nf * 16 * CTX + 32);
    f32x4 z = zero4();
    z = __builtin_amdgcn_mfma_f32_16x16x32_bf16(aq0, b0, z, 0, 0, 0);
    sc[nf] = __builtin_amdgcn_mfma_f32_16x16x32_bf16(aq1, b1, z, 0, 0, 0);
  }

  const float* mb = mbias + b * SKK + fr;
#pragma unroll
  for (int nf = 0; nf < 16; ++nf) sc[nf] = sc[nf] + mb[nf * 16];

#pragma unroll
  for (int i = 0; i < 4; ++i) {
    float m = sc[0][i];
#pragma unroll
    for (int nf = 1; nf < 16; ++nf) m = fmaxf(m, sc[nf][i]);
#pragma unroll
    for (int d = 1; d < 16; d <<= 1) m = fmaxf(m, __shfl_xor(m, d));
    float s = 0.f;
#pragma unroll
    for (int nf = 0; nf < 16; ++nf) {
      float e = __expf(sc[nf][i] - m);
      sc[nf][i] = e; s += e;
    }
#pragma unroll
    for (int d = 1; d < 16; d <<= 1) s += __shfl_xor(s, d);
    float inv = 1.0f / s;
#pragma unroll
    for (int nf = 0; nf < 16; ++nf) sc[nf][i] *= inv;
  }

  const int rbase = (lane >> 4) << 2;
#pragma unroll
  for (int nf = 0; nf < 16; ++nf) {
#pragma unroll
    for (int i = 0; i < 4; ++i) {
      int r = rbase + i;
      int col = nf * 16 + fr;
      p_lds[wid * 4096 + r * 256 + (col ^ ((r & 7) << 3))] = f2bf(sc[nf][i]);
    }
  }
  __syncthreads();

  f32x4 ov[4];
#pragma unroll
  for (int n = 0; n < 4; ++n) ov[n] = zero4();
  const u16* vpb = v2 + ((long)b * CC + h * HD + fr) * SKK;
#pragma unroll
  for (int kk = 0; kk < 8; ++kk) {
    int sb = kk * 32 + fk;
    s16x8 ap = ld8(&p_lds[wid * 4096 + fr * 256 + (sb ^ ((fr & 7) << 3))]);
#pragma unroll
    for (int n = 0; n < 4; ++n) {
      s16x8 bv = ld8(vpb + n * 16 * SKK + sb);
      ov[n] = __builtin_amdgcn_mfma_f32_16x16x32_bf16(ap, bv, ov[n], 0, 0, 0);
    }
  }
  u16* po = at + ((long)b * SS + t0 + wid * 16 + rbase) * CC + h * HD + fr;
#pragma unroll
  for (int n = 0; n < 4; ++n)
#pragma unroll
    for (int i = 0; i < 4; ++i) po[(long)i * CC + n * 16] = f2bf(ov[n][i]);
}

// ---------------- launcher ----------------
extern "C" void kernel_launch(void* const* d_in, const int* in_sizes, int n_in,
                              void* d_out, int out_size, void* d_ws, size_t ws_size,
                              hipStream_t stream) {
  const float* x       = (const float*)d_in[0];
  const float* context = (const float*)d_in[1];
  const int*   mask    = (const int*)d_in[2];
  const float* gamma_x = (const float*)d_in[3];
  const float* beta_x  = (const float*)d_in[4];
  const float* gamma_c = (const float*)d_in[5];
  const float* beta_c  = (const float*)d_in[6];
  const float* Wq      = (const float*)d_in[7];
  const float* bq      = (const float*)d_in[8];
  const float* Wkv     = (const float*)d_in[9];
  const float* bkv     = (const float*)d_in[10];
  const float* Wp      = (const float*)d_in[11];
  const float* bp      = (const float*)d_in[12];
  float* out = (float*)d_out;

  char* w = (char*)d_ws;
  size_t off = 0;
  u16* wq_bf  = (u16*)(w + off); off += (size_t)CC * CC * 2;
  u16* wkv_bf = (u16*)(w + off); off += (size_t)CTX * CTX * 2;
  u16* wp_bf  = (u16*)(w + off); off += (size_t)CC * CC * 2;
  u16* xnT    = (u16*)(w + off); off += (size_t)BB * SS * CC * 2;
  u16* ctxn   = (u16*)(w + off); off += (size_t)BB * SKK * CTX * 2;
  u16* qt     = (u16*)(w + off); off += (size_t)BB * SS * CC * 2;
  u16* kvt    = (u16*)(w + off); off += (size_t)BB * SKK * CTX * 2;
  u16* v2     = (u16*)(w + off); off += (size_t)BB * CC * SKK * 2;
  u16* at     = (u16*)(w + off); off += (size_t)BB * SS * CC * 2;
  float* mb   = (float*)(w + off); off += (size_t)BB * SKK * 4;
  float* stx  = (float*)(w + off); off += (size_t)BB * NG * 2 * 4;
  float* stc  = (float*)(w + off); off += (size_t)BB * NG * 2 * 4;
  (void)ws_size; (void)in_sizes; (void)n_in; (void)out_size;

  // weights -> bf16 (every launch: ws is re-poisoned before each timed call)
  cvt_bf16<<<1024, 256, 0, stream>>>(Wq, wq_bf, CC * CC / 4);
  cvt_bf16<<<4096, 256, 0, stream>>>(Wkv, wkv_bf, CTX * CTX / 4);
  cvt_bf16<<<1024, 256, 0, stream>>>(Wp, wp_bf, CC * CC / 4);

  // GroupNorms
  gn_stats_x<<<512, 256, 0, stream>>>(x, stx);
  gn_apply_tr_x<<<dim3(16, 16, BB), 256, 0, stream>>>(x, stx, gamma_x, beta_x, xnT);
  gn_stats_c<<<512, 256, 0, stream>>>(context, stc);
  gn_apply_c<<<8192, 256, 0, stream>>>(context, stc, gamma_c, beta_c, ctxn);
  mask_bias_k<<<16, 256, 0, stream>>>(mask, mb);

  // q_t[b][s][o] = xnT[b] @ Wq^T, epilogue (acc+bq)*ATT_SCALE -> bf16
  gemm_bt<128, 128, 0><<<dim3(8, 8, BB), 256, 0, stream>>>(
      xnT, wq_bf, qt, bq, nullptr, CC, CC, CC, CC,
      (long)SS * CC, 0, (long)SS * CC, CC, ATT_SCALE);

  // kv_t[b][s'][o2] = ctxn[b] @ Wkv^T, epilogue +bkv, scale only k-half (o2<1024)
  gemm_bt<128, 128, 0><<<dim3(2, 16, BB), 256, 0, stream>>>(
      ctxn, wkv_bf, kvt, bkv, nullptr, CTX, CTX, CTX, CTX,
      (long)SKK * CTX, 0, (long)SKK * CTX, CC, ATT_SCALE);

  transpose_v<<<dim3(16, 4, BB), 256, 0, stream>>>(kvt, v2);

  attn_fused<<<dim3(16, NH, BB), 256, 0, stream>>>(qt, kvt, v2, mb, at);

  // out[b][o][t] = x + Wp @ a + bp   (A = Wp, Bt = at[b], bias per-row, fp32 resid)
  gemm_bt<128, 128, 1><<<dim3(8, 8, BB), 256, 0, stream>>>(
      wp_bf, at, out, bp, x, CC, CC, CC, CC,
      0, (long)SS * CC, (long)SS * CC, 0, 1.0f);
}

// Round 5
// 451.528 us; speedup vs baseline: 1.1777x; 1.1777x over previous
//
#include <hip/hip_runtime.h>
#include <stdint.h>

#define DEV static __device__ __forceinline__

typedef unsigned short u16;
typedef u16  u16x8 __attribute__((ext_vector_type(8)));
typedef u16  u16x4 __attribute__((ext_vector_type(4)));
typedef float f32x4 __attribute__((ext_vector_type(4)));
typedef short s16x8 __attribute__((ext_vector_type(8)));   // 8 bf16 as shorts (guide-verified MFMA frag type)

// problem dims
#define BB 16
#define CC 1024
#define SS 1024      // Sq = 32*32
#define CTX 2048
#define SKK 256
#define NH 16
#define HD 64
#define NG 32
#define ATT_SCALE 0.35355339059327373f   // 1/64^0.25

DEV u16 f2bf(float f) {                    // fp32 -> bf16 RNE
  uint32_t u = __float_as_uint(f);
  return (u16)((u + 0x7fffu + ((u >> 16) & 1u)) >> 16);
}
DEV s16x8 ld8(const u16* p) { return __builtin_bit_cast(s16x8, *(const u16x8*)p); }
DEV f32x4 zero4() { f32x4 z = {0.f, 0.f, 0.f, 0.f}; return z; }

// async global->LDS, 16B per lane. LDS dst is wave-uniform base + lane*16.
DEV void gload_lds16(const void* g, const void* l) {
  __builtin_amdgcn_global_load_lds(
      (const __attribute__((address_space(1))) unsigned int*)(uintptr_t)g,
      (__attribute__((address_space(3))) unsigned int*)(uint32_t)(uintptr_t)l,
      16, 0, 0);
}

// ---------------- weight fp32 -> bf16 ----------------
__global__ __launch_bounds__(256) void cvt_bf16(const float* __restrict__ in,
                                                u16* __restrict__ out, int n4) {
  int i = blockIdx.x * 256 + threadIdx.x;
  if (i < n4) {
    f32x4 v = ((const f32x4*)in)[i];
    u16x4 o; o[0]=f2bf(v[0]); o[1]=f2bf(v[1]); o[2]=f2bf(v[2]); o[3]=f2bf(v[3]);
    ((u16x4*)out)[i] = o;
  }
}

// ---------------- GroupNorm stats for x ----------------
__global__ __launch_bounds__(256) void gn_stats_x(const float* __restrict__ x,
                                                  float* __restrict__ st) {
  const int b = blockIdx.x >> 5, g = blockIdx.x & 31;
  const float* p = x + ((size_t)b * CC + g * 32) * SS;
  const int tid = threadIdx.x;
  float s = 0.f, ss = 0.f;
  for (int it = 0; it < 32; ++it) {
    f32x4 v = *(const f32x4*)(p + it * 1024 + tid * 4);
    s  += v[0] + v[1] + v[2] + v[3];
    ss += v[0]*v[0] + v[1]*v[1] + v[2]*v[2] + v[3]*v[3];
  }
  __shared__ float red[512];
  red[tid] = s; red[256 + tid] = ss;
  __syncthreads();
  for (int o = 128; o > 0; o >>= 1) {
    if (tid < o) { red[tid] += red[tid + o]; red[256 + tid] += red[256 + tid + o]; }
    __syncthreads();
  }
  if (tid == 0) {
    float mean = red[0] * (1.f / 32768.f);
    float var  = red[256] * (1.f / 32768.f) - mean * mean;
    st[(b * 32 + g) * 2 + 0] = mean;
    st[(b * 32 + g) * 2 + 1] = rsqrtf(var + 1e-5f);
  }
}

// normalize x and write TRANSPOSED bf16: xnT[b][s][c]
__global__ __launch_bounds__(256) void gn_apply_tr_x(const float* __restrict__ x,
                                                     const float* __restrict__ st,
                                                     const float* __restrict__ gamma,
                                                     const float* __restrict__ beta,
                                                     u16* __restrict__ xnT) {
  __shared__ float t[64][65];
  const int b = blockIdx.z, c0 = blockIdx.y * 64, s0 = blockIdx.x * 64;
  const int tid = threadIdx.x, j = tid & 63, i0 = tid >> 6;
  for (int it = 0; it < 16; ++it) {
    int i = it * 4 + i0;
    int c = c0 + i;
    int g = c >> 5;
    float mean = st[(b * 32 + g) * 2], rstd = st[(b * 32 + g) * 2 + 1];
    float v = x[((size_t)b * CC + c) * SS + s0 + j];
    t[i][j] = (v - mean) * rstd * gamma[c] + beta[c];
  }
  __syncthreads();
  for (int it = 0; it < 16; ++it) {
    int jj = it * 4 + i0;
    xnT[((size_t)b * SS + s0 + jj) * CC + c0 + j] = f2bf(t[j][jj]);
  }
}

// ---------------- GroupNorm stats for ctx^T ----------------
__global__ __launch_bounds__(256) void gn_stats_c(const float* __restrict__ ctx,
                                                  float* __restrict__ st) {
  const int b = blockIdx.x >> 5, g = blockIdx.x & 31;
  const float* p = ctx + (size_t)b * SKK * CTX + g * 64;
  const int ch = threadIdx.x & 63, r0 = threadIdx.x >> 6;
  float s = 0.f, ss = 0.f;
  for (int it = 0; it < 64; ++it) {
    float v = p[(size_t)(it * 4 + r0) * CTX + ch];
    s += v; ss += v * v;
  }
  __shared__ float red[512];
  const int tid = threadIdx.x;
  red[tid] = s; red[256 + tid] = ss;
  __syncthreads();
  for (int o = 128; o > 0; o >>= 1) {
    if (tid < o) { red[tid] += red[tid + o]; red[256 + tid] += red[256 + tid + o]; }
    __syncthreads();
  }
  if (tid == 0) {
    float mean = red[0] * (1.f / 16384.f);
    float var  = red[256] * (1.f / 16384.f) - mean * mean;
    st[(b * 32 + g) * 2 + 0] = mean;
    st[(b * 32 + g) * 2 + 1] = rsqrtf(var + 1e-5f);
  }
}

// normalize ctx elementwise -> bf16 ctxn[b][s'][ch]
__global__ __launch_bounds__(256) void gn_apply_c(const float* __restrict__ ctx,
                                                  const float* __restrict__ st,
                                                  const float* __restrict__ gamma,
                                                  const float* __restrict__ beta,
                                                  u16* __restrict__ out) {
  size_t i = ((size_t)blockIdx.x * 256 + threadIdx.x) * 4;
  int ch = (int)(i & 2047);
  int bs = (int)(i >> 11);
  int b = bs >> 8;
  int g = ch >> 6;
  float mean = st[(b * 32 + g) * 2], rstd = st[(b * 32 + g) * 2 + 1];
  f32x4 v  = *(const f32x4*)(ctx + i);
  f32x4 ga = *(const f32x4*)(gamma + ch);
  f32x4 be = *(const f32x4*)(beta + ch);
  u16x4 o;
  o[0] = f2bf((v[0] - mean) * rstd * ga[0] + be[0]);
  o[1] = f2bf((v[1] - mean) * rstd * ga[1] + be[1]);
  o[2] = f2bf((v[2] - mean) * rstd * ga[2] + be[2]);
  o[3] = f2bf((v[3] - mean) * rstd * ga[3] + be[3]);
  *(u16x4*)(out + i) = o;
}

__global__ __launch_bounds__(256) void mask_bias_k(const int* __restrict__ mask,
                                                   float* __restrict__ mb) {
  int i = blockIdx.x * 256 + threadIdx.x;
  mb[i] = mask[i] ? 0.f : -1e9f;
}

// ---------------- generic bf16 GEMM (m97 structure) ----------------
template <int BM, int BN, int EPI>
__global__ __launch_bounds__(256) void gemm_bt(
    const u16* __restrict__ A, const u16* __restrict__ Bt, void* __restrict__ Cout,
    const float* __restrict__ bias, const float* __restrict__ resid,
    int K, int lda, int ldb, int ldc,
    long strideAb, long strideBb, long strideCb, int Nthresh, float scl) {
  constexpr int MF = BM / 32, NF = BN / 32;
  constexpr int ACH = BM / 16, BCH = BN / 16;
  __shared__ alignas(16) u16 lds_a[BM * 32];
  __shared__ alignas(16) u16 lds_b[BN * 32];
  const int tid = threadIdx.x, wid = tid >> 6, lane = tid & 63;
  const int wm = wid >> 1, wn = wid & 1;
  const int b = blockIdx.z;
  const u16* Ab = A + (long)b * strideAb + (long)blockIdx.x * BM * lda;
  const u16* Bb = Bt + (long)b * strideBb + (long)blockIdx.y * BN * ldb;
  const int srow = lane >> 2, scol = (lane & 3) * 8;
  const int fr = lane & 15, fk = (lane >> 4) * 8;

  f32x4 acc[MF][NF];
#pragma unroll
  for (int m = 0; m < MF; ++m)
#pragma unroll
    for (int n = 0; n < NF; ++n) acc[m][n] = zero4();

  for (int kt = 0; kt < K; kt += 32) {
    __syncthreads();
#pragma unroll
    for (int c = 0; c < ACH / 4; ++c) {
      int ch = wid + c * 4;
      gload_lds16(Ab + (long)(ch * 16 + srow) * lda + kt + scol, &lds_a[ch * 512]);
    }
#pragma unroll
    for (int c = 0; c < BCH / 4; ++c) {
      int ch = wid + c * 4;
      gload_lds16(Bb + (long)(ch * 16 + srow) * ldb + kt + scol, &lds_b[ch * 512]);
    }
    __syncthreads();
    s16x8 af[MF], bfr[NF];
#pragma unroll
    for (int m = 0; m < MF; ++m) af[m] = ld8(&lds_a[(wm * (BM / 2) + m * 16 + fr) * 32 + fk]);
#pragma unroll
    for (int n = 0; n < NF; ++n) bfr[n] = ld8(&lds_b[(wn * (BN / 2) + n * 16 + fr) * 32 + fk]);
#pragma unroll
    for (int m = 0; m < MF; ++m)
#pragma unroll
      for (int n = 0; n < NF; ++n)
        acc[m][n] = __builtin_amdgcn_mfma_f32_16x16x32_bf16(af[m], bfr[n], acc[m][n], 0, 0, 0);
  }

  const int rowb = blockIdx.x * BM + wm * (BM / 2) + ((lane >> 4) << 2);
  const int colb = blockIdx.y * BN + wn * (BN / 2) + fr;
#pragma unroll
  for (int m = 0; m < MF; ++m) {
#pragma unroll
    for (int n = 0; n < NF; ++n) {
      int col = colb + n * 16;
      f32x4 v = acc[m][n];
      if constexpr (EPI == 0) {
        float bia = bias[col];
        float s = (col < Nthresh) ? scl : 1.0f;
        u16* C = (u16*)Cout + (long)b * strideCb;
#pragma unroll
        for (int i = 0; i < 4; ++i) {
          int row = rowb + m * 16 + i;
          C[(long)row * ldc + col] = f2bf((v[i] + bia) * s);
        }
      } else {
        float* C = (float*)Cout + (long)b * strideCb;
        const float* R = resid + (long)b * strideCb;
#pragma unroll
        for (int i = 0; i < 4; ++i) {
          int row = rowb + m * 16 + i;
          long idx = (long)row * ldc + col;
          C[idx] = R[idx] + v[i] + bias[row];
        }
      }
    }
  }
}

// ---------------- transpose V half of kv_t -> v2[b][o(1024)][s'(256)]
__global__ __launch_bounds__(256) void transpose_v(const u16* __restrict__ kvt,
                                                   u16* __restrict__ v2) {
  __shared__ u16 t[64][66];
  const int b = blockIdx.z, s0 = blockIdx.y * 64, o0 = blockIdx.x * 64;
  const int tid = threadIdx.x, j = tid & 63, i0 = tid >> 6;
#pragma unroll
  for (int it = 0; it < 16; ++it) {
    int i = it * 4 + i0;
    t[i][j] = kvt[((long)b * SKK + s0 + i) * CTX + CC + o0 + j];
  }
  __syncthreads();
#pragma unroll
  for (int it = 0; it < 16; ++it) {
    int oi = it * 4 + i0;
    v2[((long)b * CC + o0 + oi) * SKK + s0 + j] = t[j][oi];
  }
}

// ---------------- fused attention (rewritten: LDS-staged K/V) ----------------
// Per block: one (b,h), 64 q-rows, 4 waves x 16 rows.
// Stage K[256][64] and V[64][256] into LDS via global_load_lds with XOR chunk
// swizzle pre-applied on the GLOBAL source (LDS dest stays linear, m173).
// QK^T/PV operands read as swizzled ds_read_b128 (2-way conflict = free).
// P (16x256/wave) overwrites K's LDS after one barrier; P reads are wave-private.
__global__ __launch_bounds__(256) void attn_fused(const u16* __restrict__ qt,
                                                  const u16* __restrict__ kvt,
                                                  const u16* __restrict__ v2,
                                                  const float* __restrict__ mbias,
                                                  u16* __restrict__ at) {
  __shared__ alignas(16) u16 k_lds[256 * 64];   // 32KB K, later P (8KB/wave)
  __shared__ alignas(16) u16 v_lds[64 * 256];   // 32KB V
  const int b = blockIdx.z, h = blockIdx.y, t0 = blockIdx.x * 64;
  const int tid = threadIdx.x, wid = tid >> 6, lane = tid & 63;
  const int fr = lane & 15, hi = lane >> 4;
  const int sw = fr & 7;

  // --- stage K and V (8 x 1KB chunks per wave each) ---
#pragma unroll
  for (int it = 0; it < 8; ++it) {
    int lin = (wid * 8 + it) * 1024 + lane * 16;      // byte offset in LDS
    // K: rows of 128B (64 u16); chunk = 16B; src chunk = chunk ^ (row&7)
    int kr = lin >> 7, kc = (lin >> 4) & 7;
    gload_lds16(kvt + ((long)b * SKK + kr) * CTX + h * HD + ((kc ^ (kr & 7)) << 3),
                (const char*)k_lds + (wid * 8 + it) * 1024);
    // V: rows of 512B (256 u16)
    int vr = lin >> 9, vc = (lin >> 4) & 31;
    gload_lds16(v2 + ((long)b * CC + h * HD + vr) * SKK + ((vc ^ (vr & 7)) << 3),
                (const char*)v_lds + (wid * 8 + it) * 1024);
  }

  // Q fragments (A-operand rows indexed by fr)
  const u16* qp = qt + ((long)b * SS + t0 + wid * 16 + fr) * CC + h * HD + hi * 8;
  s16x8 aq0 = ld8(qp), aq1 = ld8(qp + 32);

  __syncthreads();   // K,V staged (vmcnt drained by barrier semantics)

  // --- QK^T: sc[nf][i] = S[t=4*hi+i][s'=16*nf+fr] ---
  f32x4 sc[16];
#pragma unroll
  for (int nf = 0; nf < 16; ++nf) {
    const u16* krow = k_lds + (nf * 16 + fr) * 64;    // row r, r&7 == fr&7
    s16x8 kb0 = ld8(krow + (((hi) ^ sw) << 3));       // d 0..31
    s16x8 kb1 = ld8(krow + (((4 + hi) ^ sw) << 3));   // d 32..63
    f32x4 z = zero4();
    z = __builtin_amdgcn_mfma_f32_16x16x32_bf16(aq0, kb0, z, 0, 0, 0);
    sc[nf] = __builtin_amdgcn_mfma_f32_16x16x32_bf16(aq1, kb1, z, 0, 0, 0);
  }

  __syncthreads();   // all waves done reading K -> safe to overwrite with P

  // --- mask + softmax (rows t=4*hi+i; s' in-lane over nf, cross-lane over fr) ---
  const float* mb = mbias + b * SKK + fr;
#pragma unroll
  for (int nf = 0; nf < 16; ++nf) sc[nf] = sc[nf] + mb[nf * 16];

#pragma unroll
  for (int i = 0; i < 4; ++i) {
    float m = sc[0][i];
#pragma unroll
    for (int nf = 1; nf < 16; ++nf) m = fmaxf(m, sc[nf][i]);
#pragma unroll
    for (int d = 1; d < 16; d <<= 1) m = fmaxf(m, __shfl_xor(m, d));
    float s = 0.f;
#pragma unroll
    for (int nf = 0; nf < 16; ++nf) {
      float e = __expf(sc[nf][i] - m);
      sc[nf][i] = e; s += e;
    }
#pragma unroll
    for (int d = 1; d < 16; d <<= 1) s += __shfl_xor(s, d);
    float inv = 1.0f / s;
#pragma unroll
    for (int nf = 0; nf < 16; ++nf) sc[nf][i] *= inv;
  }

  // --- write P[t][s'] into wave-private 8KB of k_lds (rows 512B, swizzled) ---
  u16* p_base = k_lds + wid * 4096;    // u16 units: 4096 = 8KB
#pragma unroll
  for (int nf = 0; nf < 16; ++nf) {
    int c = 2 * nf + (fr >> 3);
#pragma unroll
    for (int i = 0; i < 4; ++i) {
      int t = 4 * hi + i;
      p_base[t * 256 + (((c ^ (t & 7)) << 3)) + sw] = f2bf(sc[nf][i]);
    }
  }
  // wave-private: no barrier needed (lgkmcnt ordering within wave)

  // --- PV: O[t][o] = P[t][.] x V[.][o] ---
  f32x4 ov[4];
#pragma unroll
  for (int n = 0; n < 4; ++n) ov[n] = zero4();
#pragma unroll
  for (int kk = 0; kk < 8; ++kk) {
    int c = 4 * kk + hi;
    s16x8 pa = ld8(p_base + fr * 256 + ((c ^ sw) << 3));   // P row t=fr
#pragma unroll
    for (int n = 0; n < 4; ++n) {
      int o = n * 16 + fr;                                 // o&7 == fr&7
      s16x8 vb = ld8(v_lds + o * 256 + ((c ^ sw) << 3));
      ov[n] = __builtin_amdgcn_mfma_f32_16x16x32_bf16(pa, vb, ov[n], 0, 0, 0);
    }
  }

  const int rbase = hi * 4;
  u16* po = at + ((long)b * SS + t0 + wid * 16 + rbase) * CC + h * HD + fr;
#pragma unroll
  for (int n = 0; n < 4; ++n)
#pragma unroll
    for (int i = 0; i < 4; ++i) po[(long)i * CC + n * 16] = f2bf(ov[n][i]);
}

// ---------------- launcher ----------------
extern "C" void kernel_launch(void* const* d_in, const int* in_sizes, int n_in,
                              void* d_out, int out_size, void* d_ws, size_t ws_size,
                              hipStream_t stream) {
  const float* x       = (const float*)d_in[0];
  const float* context = (const float*)d_in[1];
  const int*   mask    = (const int*)d_in[2];
  const float* gamma_x = (const float*)d_in[3];
  const float* beta_x  = (const float*)d_in[4];
  const float* gamma_c = (const float*)d_in[5];
  const float* beta_c  = (const float*)d_in[6];
  const float* Wq      = (const float*)d_in[7];
  const float* bq      = (const float*)d_in[8];
  const float* Wkv     = (const float*)d_in[9];
  const float* bkv     = (const float*)d_in[10];
  const float* Wp      = (const float*)d_in[11];
  const float* bp      = (const float*)d_in[12];
  float* out = (float*)d_out;

  char* w = (char*)d_ws;
  size_t off = 0;
  u16* wq_bf  = (u16*)(w + off); off += (size_t)CC * CC * 2;
  u16* wkv_bf = (u16*)(w + off); off += (size_t)CTX * CTX * 2;
  u16* wp_bf  = (u16*)(w + off); off += (size_t)CC * CC * 2;
  u16* xnT    = (u16*)(w + off); off += (size_t)BB * SS * CC * 2;
  u16* ctxn   = (u16*)(w + off); off += (size_t)BB * SKK * CTX * 2;
  u16* qt     = (u16*)(w + off); off += (size_t)BB * SS * CC * 2;
  u16* kvt    = (u16*)(w + off); off += (size_t)BB * SKK * CTX * 2;
  u16* v2     = (u16*)(w + off); off += (size_t)BB * CC * SKK * 2;
  u16* at     = (u16*)(w + off); off += (size_t)BB * SS * CC * 2;
  float* mb   = (float*)(w + off); off += (size_t)BB * SKK * 4;
  float* stx  = (float*)(w + off); off += (size_t)BB * NG * 2 * 4;
  float* stc  = (float*)(w + off); off += (size_t)BB * NG * 2 * 4;
  (void)ws_size; (void)in_sizes; (void)n_in; (void)out_size;

  cvt_bf16<<<1024, 256, 0, stream>>>(Wq, wq_bf, CC * CC / 4);
  cvt_bf16<<<4096, 256, 0, stream>>>(Wkv, wkv_bf, CTX * CTX / 4);
  cvt_bf16<<<1024, 256, 0, stream>>>(Wp, wp_bf, CC * CC / 4);

  gn_stats_x<<<512, 256, 0, stream>>>(x, stx);
  gn_apply_tr_x<<<dim3(16, 16, BB), 256, 0, stream>>>(x, stx, gamma_x, beta_x, xnT);
  gn_stats_c<<<512, 256, 0, stream>>>(context, stc);
  gn_apply_c<<<8192, 256, 0, stream>>>(context, stc, gamma_c, beta_c, ctxn);
  mask_bias_k<<<16, 256, 0, stream>>>(mask, mb);

  gemm_bt<128, 128, 0><<<dim3(8, 8, BB), 256, 0, stream>>>(
      xnT, wq_bf, qt, bq, nullptr, CC, CC, CC, CC,
      (long)SS * CC, 0, (long)SS * CC, CC, ATT_SCALE);

  gemm_bt<128, 128, 0><<<dim3(2, 16, BB), 256, 0, stream>>>(
      ctxn, wkv_bf, kvt, bkv, nullptr, CTX, CTX, CTX, CTX,
      (long)SKK * CTX, 0, (long)SKK * CTX, CC, ATT_SCALE);

  transpose_v<<<dim3(16, 4, BB), 256, 0, stream>>>(kvt, v2);

  attn_fused<<<dim3(16, NH, BB), 256, 0, stream>>>(qt, kvt, v2, mb, at);

  gemm_bt<128, 128, 1><<<dim3(8, 8, BB), 256, 0, stream>>>(
      wp_bf, at, out, bp, x, CC, CC, CC, CC,
      0, (long)SS * CC, (long)SS * CC, 0, 1.0f);
}

// Round 6
// 445.827 us; speedup vs baseline: 1.1928x; 1.0128x over previous
//
#include <hip/hip_runtime.h>
#include <stdint.h>

#define DEV static __device__ __forceinline__

typedef unsigned short u16;
typedef u16  u16x8 __attribute__((ext_vector_type(8)));
typedef u16  u16x4 __attribute__((ext_vector_type(4)));
typedef float f32x4 __attribute__((ext_vector_type(4)));
typedef short s16x8 __attribute__((ext_vector_type(8)));   // 8 bf16 as shorts

// problem dims
#define BB 16
#define CC 1024
#define SS 1024      // Sq = 32*32
#define CTX 2048
#define SKK 256
#define NH 16
#define HD 64
#define NG 32
#define ATT_SCALE 0.35355339059327373f   // 1/64^0.25

DEV u16 f2bf(float f) {                    // fp32 -> bf16 RNE
  uint32_t u = __float_as_uint(f);
  return (u16)((u + 0x7fffu + ((u >> 16) & 1u)) >> 16);
}
DEV s16x8 ld8(const u16* p) { return __builtin_bit_cast(s16x8, *(const u16x8*)p); }
DEV f32x4 zero4() { f32x4 z = {0.f, 0.f, 0.f, 0.f}; return z; }

// async global->LDS, 16B per lane. LDS dst is wave-uniform base + lane*16.
DEV void gload_lds16(const void* g, const void* l) {
  __builtin_amdgcn_global_load_lds(
      (const __attribute__((address_space(1))) unsigned int*)(uintptr_t)g,
      (__attribute__((address_space(3))) unsigned int*)(uint32_t)(uintptr_t)l,
      16, 0, 0);
}

// ---------------- prep: weights fp32->bf16 (3 tensors) + mask bias ----------------
// range-dispatched on blockIdx.x to cut launch count (13 -> 8 dispatches total)
__global__ __launch_bounds__(256) void prep_misc(const float* __restrict__ Wq,
                                                 const float* __restrict__ Wkv,
                                                 const float* __restrict__ Wp,
                                                 const int* __restrict__ mask,
                                                 u16* __restrict__ wq_bf,
                                                 u16* __restrict__ wkv_bf,
                                                 u16* __restrict__ wp_bf,
                                                 float* __restrict__ mb) {
  const int bid = blockIdx.x, tid = threadIdx.x;
  const float* src; u16* dst; int i;
  if (bid < 1024)      { src = Wq;  dst = wq_bf;  i = bid * 256 + tid; }
  else if (bid < 5120) { src = Wkv; dst = wkv_bf; i = (bid - 1024) * 256 + tid; }
  else if (bid < 6144) { src = Wp;  dst = wp_bf;  i = (bid - 5120) * 256 + tid; }
  else {
    int j = (bid - 6144) * 256 + tid;
    mb[j] = mask[j] ? 0.f : -1e9f;
    return;
  }
  f32x4 v = ((const f32x4*)src)[i];
  u16x4 o; o[0]=f2bf(v[0]); o[1]=f2bf(v[1]); o[2]=f2bf(v[2]); o[3]=f2bf(v[3]);
  ((u16x4*)dst)[i] = o;
}

// ---------------- GroupNorm stats (x part: blocks 0..511, ctx part: 512..1023) ----
__global__ __launch_bounds__(256) void gn_stats_all(const float* __restrict__ x,
                                                    const float* __restrict__ ctx,
                                                    float* __restrict__ stx,
                                                    float* __restrict__ stc) {
  const int bid = blockIdx.x, tid = threadIdx.x;
  float s = 0.f, ss = 0.f;
  float* st; int slot; float inv_n;
  if (bid < 512) {
    const int b = bid >> 5, g = bid & 31;
    const float* p = x + ((size_t)b * CC + g * 32) * SS;
    for (int it = 0; it < 32; ++it) {
      f32x4 v = *(const f32x4*)(p + it * 1024 + tid * 4);
      s  += v[0] + v[1] + v[2] + v[3];
      ss += v[0]*v[0] + v[1]*v[1] + v[2]*v[2] + v[3]*v[3];
    }
    st = stx; slot = bid; inv_n = 1.f / 32768.f;
  } else {
    const int bid2 = bid - 512;
    const int b = bid2 >> 5, g = bid2 & 31;
    const float* p = ctx + (size_t)b * SKK * CTX + g * 64;
    const int ch = tid & 63, r0 = tid >> 6;
    for (int it = 0; it < 64; ++it) {
      float v = p[(size_t)(it * 4 + r0) * CTX + ch];
      s += v; ss += v * v;
    }
    st = stc; slot = bid2; inv_n = 1.f / 16384.f;
  }
  __shared__ float red[512];
  red[tid] = s; red[256 + tid] = ss;
  __syncthreads();
  for (int o = 128; o > 0; o >>= 1) {
    if (tid < o) { red[tid] += red[tid + o]; red[256 + tid] += red[256 + tid + o]; }
    __syncthreads();
  }
  if (tid == 0) {
    float mean = red[0] * inv_n;
    float var  = red[256] * inv_n - mean * mean;
    st[slot * 2 + 0] = mean;
    st[slot * 2 + 1] = rsqrtf(var + 1e-5f);
  }
}

// ---------------- GroupNorm apply (ctx part: blocks 0..8191; x-transpose: 8192..) --
__global__ __launch_bounds__(256) void gn_apply_all(const float* __restrict__ x,
                                                    const float* __restrict__ ctx,
                                                    const float* __restrict__ stx,
                                                    const float* __restrict__ stc,
                                                    const float* __restrict__ gamma_x,
                                                    const float* __restrict__ beta_x,
                                                    const float* __restrict__ gamma_c,
                                                    const float* __restrict__ beta_c,
                                                    u16* __restrict__ xnT,
                                                    u16* __restrict__ ctxn) {
  __shared__ float t[64][65];
  const int bid = blockIdx.x, tid = threadIdx.x;
  if (bid < 8192) {
    size_t i = ((size_t)bid * 256 + tid) * 4;
    int ch = (int)(i & 2047);
    int bs = (int)(i >> 11);
    int b = bs >> 8;
    int g = ch >> 6;
    float mean = stc[(b * 32 + g) * 2], rstd = stc[(b * 32 + g) * 2 + 1];
    f32x4 v  = *(const f32x4*)(ctx + i);
    f32x4 ga = *(const f32x4*)(gamma_c + ch);
    f32x4 be = *(const f32x4*)(beta_c + ch);
    u16x4 o;
    o[0] = f2bf((v[0] - mean) * rstd * ga[0] + be[0]);
    o[1] = f2bf((v[1] - mean) * rstd * ga[1] + be[1]);
    o[2] = f2bf((v[2] - mean) * rstd * ga[2] + be[2]);
    o[3] = f2bf((v[3] - mean) * rstd * ga[3] + be[3]);
    *(u16x4*)(ctxn + i) = o;
    return;
  }
  const int id2 = bid - 8192;                       // [0, 4096)
  const int b = id2 >> 8, c0 = ((id2 >> 4) & 15) * 64, s0 = (id2 & 15) * 64;
  const int j = tid & 63, i0 = tid >> 6;
  for (int it = 0; it < 16; ++it) {
    int i = it * 4 + i0;
    int c = c0 + i;
    int g = c >> 5;
    float mean = stx[(b * 32 + g) * 2], rstd = stx[(b * 32 + g) * 2 + 1];
    float v = x[((size_t)b * CC + c) * SS + s0 + j];
    t[i][j] = (v - mean) * rstd * gamma_x[c] + beta_x[c];
  }
  __syncthreads();
  for (int it = 0; it < 16; ++it) {
    int jj = it * 4 + i0;
    xnT[((size_t)b * SS + s0 + jj) * CC + c0 + j] = f2bf(t[j][jj]);
  }
}

// ---------------- generic bf16 GEMM (m97 structure) + XCD chunk swizzle -----------
template <int BM, int BN, int EPI>
__global__ __launch_bounds__(256) void gemm_bt(
    const u16* __restrict__ A, const u16* __restrict__ Bt, void* __restrict__ Cout,
    const float* __restrict__ bias, const float* __restrict__ resid,
    int K, int lda, int ldb, int ldc,
    long strideAb, long strideBb, long strideCb, int Nthresh, float scl) {
  constexpr int MF = BM / 32, NF = BN / 32;
  constexpr int ACH = BM / 16, BCH = BN / 16;
  __shared__ alignas(16) u16 lds_a[BM * 32];
  __shared__ alignas(16) u16 lds_b[BN * 32];
  const int tid = threadIdx.x, wid = tid >> 6, lane = tid & 63;
  const int wm = wid >> 1, wn = wid & 1;

  // bijective XCD chunk swizzle (all grids are multiples of 8): XCD k gets a
  // contiguous batch-major chunk -> per-batch A/B panels stay in its 4MB L2.
  const int nwg  = gridDim.x * gridDim.y * gridDim.z;
  const int orig = blockIdx.x + gridDim.x * (blockIdx.y + gridDim.y * blockIdx.z);
  const int v    = (orig & 7) * (nwg >> 3) + (orig >> 3);
  const int gxy  = gridDim.x * gridDim.y;
  const int bz   = v / gxy;
  const int rr   = v - bz * gxy;
  const int by   = rr / gridDim.x;
  const int bx   = rr - by * gridDim.x;

  const u16* Ab = A + (long)bz * strideAb + (long)bx * BM * lda;
  const u16* Bb = Bt + (long)bz * strideBb + (long)by * BN * ldb;
  const int srow = lane >> 2, scol = (lane & 3) * 8;
  const int fr = lane & 15, fk = (lane >> 4) * 8;

  f32x4 acc[MF][NF];
#pragma unroll
  for (int m = 0; m < MF; ++m)
#pragma unroll
    for (int n = 0; n < NF; ++n) acc[m][n] = zero4();

  for (int kt = 0; kt < K; kt += 32) {
    __syncthreads();
#pragma unroll
    for (int c = 0; c < ACH / 4; ++c) {
      int ch = wid + c * 4;
      gload_lds16(Ab + (long)(ch * 16 + srow) * lda + kt + scol, &lds_a[ch * 512]);
    }
#pragma unroll
    for (int c = 0; c < BCH / 4; ++c) {
      int ch = wid + c * 4;
      gload_lds16(Bb + (long)(ch * 16 + srow) * ldb + kt + scol, &lds_b[ch * 512]);
    }
    __syncthreads();
    s16x8 af[MF], bfr[NF];
#pragma unroll
    for (int m = 0; m < MF; ++m) af[m] = ld8(&lds_a[(wm * (BM / 2) + m * 16 + fr) * 32 + fk]);
#pragma unroll
    for (int n = 0; n < NF; ++n) bfr[n] = ld8(&lds_b[(wn * (BN / 2) + n * 16 + fr) * 32 + fk]);
#pragma unroll
    for (int m = 0; m < MF; ++m)
#pragma unroll
      for (int n = 0; n < NF; ++n)
        acc[m][n] = __builtin_amdgcn_mfma_f32_16x16x32_bf16(af[m], bfr[n], acc[m][n], 0, 0, 0);
  }

  const int rowb = bx * BM + wm * (BM / 2) + ((lane >> 4) << 2);
  const int colb = by * BN + wn * (BN / 2) + fr;
#pragma unroll
  for (int m = 0; m < MF; ++m) {
#pragma unroll
    for (int n = 0; n < NF; ++n) {
      int col = colb + n * 16;
      f32x4 vv = acc[m][n];
      if constexpr (EPI == 0) {
        float bia = bias[col];
        float s = (col < Nthresh) ? scl : 1.0f;
        u16* C = (u16*)Cout + (long)bz * strideCb;
#pragma unroll
        for (int i = 0; i < 4; ++i) {
          int row = rowb + m * 16 + i;
          C[(long)row * ldc + col] = f2bf((vv[i] + bia) * s);
        }
      } else {
        float* C = (float*)Cout + (long)bz * strideCb;
        const float* R = resid + (long)bz * strideCb;
#pragma unroll
        for (int i = 0; i < 4; ++i) {
          int row = rowb + m * 16 + i;
          long idx = (long)row * ldc + col;
          C[idx] = R[idx] + vv[i] + bias[row];
        }
      }
    }
  }
}

// ---------------- transpose V half of kv_t -> v2[b][o(1024)][s'(256)]
__global__ __launch_bounds__(256) void transpose_v(const u16* __restrict__ kvt,
                                                   u16* __restrict__ v2) {
  __shared__ u16 t[64][66];
  const int b = blockIdx.z, s0 = blockIdx.y * 64, o0 = blockIdx.x * 64;
  const int tid = threadIdx.x, j = tid & 63, i0 = tid >> 6;
#pragma unroll
  for (int it = 0; it < 16; ++it) {
    int i = it * 4 + i0;
    t[i][j] = kvt[((long)b * SKK + s0 + i) * CTX + CC + o0 + j];
  }
  __syncthreads();
#pragma unroll
  for (int it = 0; it < 16; ++it) {
    int oi = it * 4 + i0;
    v2[((long)b * CC + o0 + oi) * SKK + s0 + j] = t[j][oi];
  }
}

// ---------------- fused attention (LDS-staged K/V, XCD chunk swizzle) -------------
__global__ __launch_bounds__(256) void attn_fused(const u16* __restrict__ qt,
                                                  const u16* __restrict__ kvt,
                                                  const u16* __restrict__ v2,
                                                  const float* __restrict__ mbias,
                                                  u16* __restrict__ at) {
  __shared__ alignas(16) u16 k_lds[256 * 64];   // 32KB K, later P (8KB/wave)
  __shared__ alignas(16) u16 v_lds[64 * 256];   // 32KB V
  // chunk swizzle over flat 4096 blocks: XCD k gets 512 contiguous (b,h,x) ids
  const int orig = blockIdx.x + 16 * blockIdx.y + 256 * blockIdx.z;
  const int v = (orig & 7) * 512 + (orig >> 3);
  const int bb = v >> 8, h = (v >> 4) & 15, t0 = (v & 15) * 64;

  const int tid = threadIdx.x, wid = tid >> 6, lane = tid & 63;
  const int fr = lane & 15, hi = lane >> 4;
  const int sw = fr & 7;

  // --- stage K and V (8 x 1KB chunks per wave each), XOR-swizzled global src ---
#pragma unroll
  for (int it = 0; it < 8; ++it) {
    int lin = (wid * 8 + it) * 1024 + lane * 16;      // byte offset in LDS
    int kr = lin >> 7, kc = (lin >> 4) & 7;
    gload_lds16(kvt + ((long)bb * SKK + kr) * CTX + h * HD + ((kc ^ (kr & 7)) << 3),
                (const char*)k_lds + (wid * 8 + it) * 1024);
    int vr = lin >> 9, vc = (lin >> 4) & 31;
    gload_lds16(v2 + ((long)bb * CC + h * HD + vr) * SKK + ((vc ^ (vr & 7)) << 3),
                (const char*)v_lds + (wid * 8 + it) * 1024);
  }

  const u16* qp = qt + ((long)bb * SS + t0 + wid * 16 + fr) * CC + h * HD + hi * 8;
  s16x8 aq0 = ld8(qp), aq1 = ld8(qp + 32);

  __syncthreads();

  // --- QK^T ---
  f32x4 sc[16];
#pragma unroll
  for (int nf = 0; nf < 16; ++nf) {
    const u16* krow = k_lds + (nf * 16 + fr) * 64;
    s16x8 kb0 = ld8(krow + (((hi) ^ sw) << 3));
    s16x8 kb1 = ld8(krow + (((4 + hi) ^ sw) << 3));
    f32x4 z = zero4();
    z = __builtin_amdgcn_mfma_f32_16x16x32_bf16(aq0, kb0, z, 0, 0, 0);
    sc[nf] = __builtin_amdgcn_mfma_f32_16x16x32_bf16(aq1, kb1, z, 0, 0, 0);
  }

  __syncthreads();   // all waves done reading K -> safe to overwrite with P

  // --- mask + softmax ---
  const float* mb = mbias + bb * SKK + fr;
#pragma unroll
  for (int nf = 0; nf < 16; ++nf) sc[nf] = sc[nf] + mb[nf * 16];

#pragma unroll
  for (int i = 0; i < 4; ++i) {
    float m = sc[0][i];
#pragma unroll
    for (int nf = 1; nf < 16; ++nf) m = fmaxf(m, sc[nf][i]);
#pragma unroll
    for (int d = 1; d < 16; d <<= 1) m = fmaxf(m, __shfl_xor(m, d));
    float s = 0.f;
#pragma unroll
    for (int nf = 0; nf < 16; ++nf) {
      float e = __expf(sc[nf][i] - m);
      sc[nf][i] = e; s += e;
    }
#pragma unroll
    for (int d = 1; d < 16; d <<= 1) s += __shfl_xor(s, d);
    float inv = 1.0f / s;
#pragma unroll
    for (int nf = 0; nf < 16; ++nf) sc[nf][i] *= inv;
  }

  // --- write P into wave-private 8KB of k_lds (swizzled) ---
  u16* p_base = k_lds + wid * 4096;
#pragma unroll
  for (int nf = 0; nf < 16; ++nf) {
    int c = 2 * nf + (fr >> 3);
#pragma unroll
    for (int i = 0; i < 4; ++i) {
      int t = 4 * hi + i;
      p_base[t * 256 + (((c ^ (t & 7)) << 3)) + sw] = f2bf(sc[nf][i]);
    }
  }

  // --- PV ---
  f32x4 ov[4];
#pragma unroll
  for (int n = 0; n < 4; ++n) ov[n] = zero4();
#pragma unroll
  for (int kk = 0; kk < 8; ++kk) {
    int c = 4 * kk + hi;
    s16x8 pa = ld8(p_base + fr * 256 + ((c ^ sw) << 3));
#pragma unroll
    for (int n = 0; n < 4; ++n) {
      int o = n * 16 + fr;
      s16x8 vb = ld8(v_lds + o * 256 + ((c ^ sw) << 3));
      ov[n] = __builtin_amdgcn_mfma_f32_16x16x32_bf16(pa, vb, ov[n], 0, 0, 0);
    }
  }

  const int rbase = hi * 4;
  u16* po = at + ((long)bb * SS + t0 + wid * 16 + rbase) * CC + h * HD + fr;
#pragma unroll
  for (int n = 0; n < 4; ++n)
#pragma unroll
    for (int i = 0; i < 4; ++i) po[(long)i * CC + n * 16] = f2bf(ov[n][i]);
}

// ---------------- launcher ----------------
extern "C" void kernel_launch(void* const* d_in, const int* in_sizes, int n_in,
                              void* d_out, int out_size, void* d_ws, size_t ws_size,
                              hipStream_t stream) {
  const float* x       = (const float*)d_in[0];
  const float* context = (const float*)d_in[1];
  const int*   mask    = (const int*)d_in[2];
  const float* gamma_x = (const float*)d_in[3];
  const float* beta_x  = (const float*)d_in[4];
  const float* gamma_c = (const float*)d_in[5];
  const float* beta_c  = (const float*)d_in[6];
  const float* Wq      = (const float*)d_in[7];
  const float* bq      = (const float*)d_in[8];
  const float* Wkv     = (const float*)d_in[9];
  const float* bkv     = (const float*)d_in[10];
  const float* Wp      = (const float*)d_in[11];
  const float* bp      = (const float*)d_in[12];
  float* out = (float*)d_out;

  char* w = (char*)d_ws;
  size_t off = 0;
  u16* wq_bf  = (u16*)(w + off); off += (size_t)CC * CC * 2;
  u16* wkv_bf = (u16*)(w + off); off += (size_t)CTX * CTX * 2;
  u16* wp_bf  = (u16*)(w + off); off += (size_t)CC * CC * 2;
  u16* xnT    = (u16*)(w + off); off += (size_t)BB * SS * CC * 2;
  u16* ctxn   = (u16*)(w + off); off += (size_t)BB * SKK * CTX * 2;
  u16* qt     = (u16*)(w + off); off += (size_t)BB * SS * CC * 2;
  u16* kvt    = (u16*)(w + off); off += (size_t)BB * SKK * CTX * 2;
  u16* v2     = (u16*)(w + off); off += (size_t)BB * CC * SKK * 2;
  u16* at     = (u16*)(w + off); off += (size_t)BB * SS * CC * 2;
  float* mb   = (float*)(w + off); off += (size_t)BB * SKK * 4;
  float* stx  = (float*)(w + off); off += (size_t)BB * NG * 2 * 4;
  float* stc  = (float*)(w + off); off += (size_t)BB * NG * 2 * 4;
  (void)ws_size; (void)in_sizes; (void)n_in; (void)out_size;

  // 1) prep: weight cvt x3 + mask bias
  prep_misc<<<6160, 256, 0, stream>>>(Wq, Wkv, Wp, mask, wq_bf, wkv_bf, wp_bf, mb);

  // 2) GN stats (x + ctx)
  gn_stats_all<<<1024, 256, 0, stream>>>(x, context, stx, stc);

  // 3) GN apply (ctx elementwise + x transpose)
  gn_apply_all<<<12288, 256, 0, stream>>>(x, context, stx, stc,
                                          gamma_x, beta_x, gamma_c, beta_c,
                                          xnT, ctxn);

  // 4) q_t = xnT @ Wq^T, epilogue (acc+bq)*ATT_SCALE -> bf16
  gemm_bt<128, 128, 0><<<dim3(8, 8, BB), 256, 0, stream>>>(
      xnT, wq_bf, qt, bq, nullptr, CC, CC, CC, CC,
      (long)SS * CC, 0, (long)SS * CC, CC, ATT_SCALE);

  // 5) kv_t = ctxn @ Wkv^T, epilogue +bkv, scale only k-half
  gemm_bt<128, 128, 0><<<dim3(2, 16, BB), 256, 0, stream>>>(
      ctxn, wkv_bf, kvt, bkv, nullptr, CTX, CTX, CTX, CTX,
      (long)SKK * CTX, 0, (long)SKK * CTX, CC, ATT_SCALE);

  // 6) V transpose
  transpose_v<<<dim3(16, 4, BB), 256, 0, stream>>>(kvt, v2);

  // 7) fused attention
  attn_fused<<<dim3(16, NH, BB), 256, 0, stream>>>(qt, kvt, v2, mb, at);

  // 8) out = x + Wp @ a + bp
  gemm_bt<128, 128, 1><<<dim3(8, 8, BB), 256, 0, stream>>>(
      wp_bf, at, out, bp, x, CC, CC, CC, CC,
      0, (long)SS * CC, (long)SS * CC, 0, 1.0f);
}